// Round 18
// baseline (86.828 us; speedup 1.0000x reference)
//
#include <hip/hip_runtime.h>
#include <stdint.h>

typedef __attribute__((ext_vector_type(4))) float f32x4;
typedef __attribute__((ext_vector_type(16))) float f32x16;
typedef __attribute__((ext_vector_type(8))) short bf16x8;
typedef __attribute__((ext_vector_type(4))) unsigned short u16x4;

__device__ __forceinline__ unsigned short f2bf(float f) {
    unsigned int u = __builtin_bit_cast(unsigned int, f);
    u += 0x7fffu + ((u >> 16) & 1u);
    return (unsigned short)(u >> 16);
}
__device__ __forceinline__ float bf2f(unsigned short s) {
    unsigned int u = ((unsigned int)s) << 16;
    return __builtin_bit_cast(float, u);
}
__device__ __forceinline__ float fexp2(float x) {
#if __has_builtin(__builtin_amdgcn_exp2f)
    return __builtin_amdgcn_exp2f(x);
#else
    return exp2f(x);
#endif
}
__device__ __forceinline__ unsigned int cvt_pk_bf16(float lo, float hi) {
    unsigned int r;
    asm("v_cvt_pk_bf16_f32 %0, %1, %2" : "=v"(r) : "v"(lo), "v"(hi));
    return r;
}

// ---------------- fused f32 -> bf16 convert of x, qkv_w, out_w ----------------
__global__ void k_cvt3(const float* __restrict__ x,
                       const float* __restrict__ w1,
                       const float* __restrict__ w2,
                       unsigned short* __restrict__ out) {
    const int C1 = 1048576;            // x chunks (8192*512/4)
    const int C2 = 196608;             // w1 chunks (1536*512/4)
    int i = blockIdx.x * blockDim.x + threadIdx.x;
    f32x4 v;
    if (i < C1)            v = ((const f32x4*)x)[i];
    else if (i < C1 + C2)  v = ((const f32x4*)w1)[i - C1];
    else                   v = ((const f32x4*)w2)[i - C1 - C2];
    u16x4 o;
    o.x = f2bf(v.x); o.y = f2bf(v.y); o.z = f2bf(v.z); o.w = f2bf(v.w);
    ((u16x4*)out)[i] = o;
}

// ---------------- GEMM1 + fused rotary/split/transpose epilogue ----------------
__global__ __launch_bounds__(256, 3)
void k_gemm_qkv(const unsigned short* __restrict__ A,
                const unsigned short* __restrict__ Bm,
                const float* __restrict__ bias,
                const float* __restrict__ pos,
                unsigned short* __restrict__ Qb,
                unsigned short* __restrict__ Kb,
                unsigned short* __restrict__ VT) {
    const float PI = 3.14159265358979323846f;
    const float QS = 0.04419417382415922f * 1.44269504088896341f;  // scale * log2(e)
    const int K = 512;
    __shared__ unsigned short As[3][128 * 32];
    __shared__ unsigned short Bs[3][128 * 32];
    const int tid = threadIdx.x;
    const int lane = tid & 63;
    const int w = tid >> 6;
    const int wr = (w >> 1) * 64, wc = (w & 1) * 64;
    const int g = lane >> 4, fr = lane & 15;

    const int bid = blockIdx.x;
    const int xcd = bid & 7, loc = bid >> 3;
    const int rowb = xcd * 8 + (loc & 7);
    const int colb = loc >> 3;                 // 0..11

    f32x4 acc[4][4];
#pragma unroll
    for (int i = 0; i < 4; ++i)
#pragma unroll
        for (int j = 0; j < 4; ++j) acc[i][j] = f32x4{0.f, 0.f, 0.f, 0.f};

    const int srow16 = lane >> 2;
    const int schunk = ((lane & 3) ^ (srow16 & 3)) * 8;
    const int sA = w, sB = w + 4;
    const unsigned short* Aseg0 = A + (size_t)(rowb * 128 + sA * 16 + srow16) * K + schunk;
    const unsigned short* Aseg1 = A + (size_t)(rowb * 128 + sB * 16 + srow16) * K + schunk;
    const unsigned short* Bseg0 = Bm + (size_t)(colb * 128 + sA * 16 + srow16) * K + schunk;
    const unsigned short* Bseg1 = Bm + (size_t)(colb * 128 + sB * 16 + srow16) * K + schunk;

    auto stage = [&](int bsel, int k0) {
        char* la = (char*)&As[bsel][0];
        char* lb = (char*)&Bs[bsel][0];
        __builtin_amdgcn_global_load_lds((const __attribute__((address_space(1))) void*)(Aseg0 + k0),
                                         (__attribute__((address_space(3))) void*)(la + sA * 1024), 16, 0, 0);
        __builtin_amdgcn_global_load_lds((const __attribute__((address_space(1))) void*)(Aseg1 + k0),
                                         (__attribute__((address_space(3))) void*)(la + sB * 1024), 16, 0, 0);
        __builtin_amdgcn_global_load_lds((const __attribute__((address_space(1))) void*)(Bseg0 + k0),
                                         (__attribute__((address_space(3))) void*)(lb + sA * 1024), 16, 0, 0);
        __builtin_amdgcn_global_load_lds((const __attribute__((address_space(1))) void*)(Bseg1 + k0),
                                         (__attribute__((address_space(3))) void*)(lb + sB * 1024), 16, 0, 0);
    };
    auto compute = [&](int bsel) {
        bf16x8 af[4], bfv[4];
        const int rc = (g ^ (fr & 3)) * 8;
#pragma unroll
        for (int mi = 0; mi < 4; ++mi)
            af[mi] = *(const bf16x8*)&As[bsel][(wr + mi * 16 + fr) * 32 + rc];
#pragma unroll
        for (int ni = 0; ni < 4; ++ni)
            bfv[ni] = *(const bf16x8*)&Bs[bsel][(wc + ni * 16 + fr) * 32 + rc];
        __builtin_amdgcn_s_setprio(1);
#pragma unroll
        for (int mi = 0; mi < 4; ++mi)
#pragma unroll
            for (int ni = 0; ni < 4; ++ni)
                acc[mi][ni] = __builtin_amdgcn_mfma_f32_16x16x32_bf16(af[mi], bfv[ni], acc[mi][ni], 0, 0, 0);
        __builtin_amdgcn_s_setprio(0);
    };

    const int nt = K >> 5;
    stage(0, 0);
    stage(1, 32);
    int cur = 0;
#pragma unroll 1
    for (int t = 0; t < nt; ++t) {
        if (t < nt - 1) asm volatile("s_waitcnt vmcnt(4)" ::: "memory");
        else            asm volatile("s_waitcnt vmcnt(0)" ::: "memory");
        __builtin_amdgcn_s_barrier();
        compute(cur);
        if (t + 2 < nt) {
            int nxt = cur + 2; if (nxt >= 3) nxt -= 3;
            stage(nxt, (t + 2) << 5);
        }
        cur = (cur + 1 == 3) ? 0 : cur + 1;
    }

    const int jrot = (fr < 3) ? fr : ((fr < 6) ? fr - 3 : 0);
    const int shbase = lane & 48;
#pragma unroll
    for (int mi = 0; mi < 4; ++mi) {
#pragma unroll
        for (int ni = 0; ni < 4; ++ni) {
            int row = rowb * 128 + wr + mi * 16 + g * 4;
            int col = colb * 128 + wc + ni * 16 + fr;
            float bz = bias[col];
            float v[4];
#pragma unroll
            for (int r = 0; r < 4; ++r) v[r] = acc[mi][ni][r] + bz;
            int b = row >> 11, n = row & 2047;
            if (colb < 8) {
                const int isQ = (colb < 4);
                int qcol = isQ ? col : col - 512;
                int h = qcol >> 6, dh = qcol & 63;
                if (ni == 0) {   // dh 0..15 sub-block: rotate dh<6
#pragma unroll
                    for (int r = 0; r < 4; ++r) {
                        float x1 = __shfl(v[r], shbase + 2 * jrot, 64);
                        float x2 = __shfl(v[r], shbase + 2 * jrot + 1, 64);
                        if (fr < 6) {
                            float th = pos[(row + r) * 3 + jrot] * PI;
                            float sn = __sinf(th), cs = __cosf(th);
                            v[r] = (fr < 3) ? (x1 * cs - x2 * sn) : (x1 * sn + x2 * cs);
                        }
                    }
                }
                float qs = isQ ? QS : 1.f;
                unsigned short* dst = isQ ? Qb : Kb;
                size_t rb = (size_t)(b * 8 + h) * 2048 + n;
#pragma unroll
                for (int r = 0; r < 4; ++r)
                    dst[(rb + r) * 64 + dh] = f2bf(v[r] * qs);
            } else {
                int vcol = col - 1024;
                int h = vcol >> 6, dh = vcol & 63;
                int q2 = (n >> 2) & 3;
                int np = n + (q2 == 1 ? 4 : (q2 == 2 ? -4 : 0));
                u16x4 o;
#pragma unroll
                for (int r = 0; r < 4; ++r) o[r] = f2bf(v[r]);
                *(u16x4*)&VT[((size_t)(b * 8 + h) * 64 + dh) * 2048 + np] = o;
            }
        }
    }
}

// ---------------- NT GEMM (out-proj): BK=32, 3-buffer, XCD-grouped ----------------
__global__ __launch_bounds__(256, 3)
void k_gemm_out(const unsigned short* __restrict__ A,
                const unsigned short* __restrict__ Bm,
                const float* __restrict__ bias,
                float* __restrict__ Cout, int M, int N, int K) {
    __shared__ unsigned short As[3][128 * 32];
    __shared__ unsigned short Bs[3][128 * 32];
    const int tid = threadIdx.x;
    const int lane = tid & 63;
    const int w = tid >> 6;
    const int wr = (w >> 1) * 64, wc = (w & 1) * 64;
    const int g = lane >> 4, fr = lane & 15;

    const int bid = blockIdx.x;
    const int xcd = bid & 7, loc = bid >> 3;
    const int rowb = xcd * 8 + (loc & 7);
    const int colb = loc >> 3;

    f32x4 acc[4][4];
#pragma unroll
    for (int i = 0; i < 4; ++i)
#pragma unroll
        for (int j = 0; j < 4; ++j) acc[i][j] = f32x4{0.f, 0.f, 0.f, 0.f};

    const int srow16 = lane >> 2;
    const int schunk = ((lane & 3) ^ (srow16 & 3)) * 8;
    const int sA = w, sB = w + 4;
    const unsigned short* Aseg0 = A + (size_t)(rowb * 128 + sA * 16 + srow16) * K + schunk;
    const unsigned short* Aseg1 = A + (size_t)(rowb * 128 + sB * 16 + srow16) * K + schunk;
    const unsigned short* Bseg0 = Bm + (size_t)(colb * 128 + sA * 16 + srow16) * K + schunk;
    const unsigned short* Bseg1 = Bm + (size_t)(colb * 128 + sB * 16 + srow16) * K + schunk;

    auto stage = [&](int bsel, int k0) {
        char* la = (char*)&As[bsel][0];
        char* lb = (char*)&Bs[bsel][0];
        __builtin_amdgcn_global_load_lds((const __attribute__((address_space(1))) void*)(Aseg0 + k0),
                                         (__attribute__((address_space(3))) void*)(la + sA * 1024), 16, 0, 0);
        __builtin_amdgcn_global_load_lds((const __attribute__((address_space(1))) void*)(Aseg1 + k0),
                                         (__attribute__((address_space(3))) void*)(la + sB * 1024), 16, 0, 0);
        __builtin_amdgcn_global_load_lds((const __attribute__((address_space(1))) void*)(Bseg0 + k0),
                                         (__attribute__((address_space(3))) void*)(lb + sA * 1024), 16, 0, 0);
        __builtin_amdgcn_global_load_lds((const __attribute__((address_space(1))) void*)(Bseg1 + k0),
                                         (__attribute__((address_space(3))) void*)(lb + sB * 1024), 16, 0, 0);
    };
    auto compute = [&](int bsel) {
        bf16x8 af[4], bfv[4];
        const int rc = (g ^ (fr & 3)) * 8;
#pragma unroll
        for (int mi = 0; mi < 4; ++mi)
            af[mi] = *(const bf16x8*)&As[bsel][(wr + mi * 16 + fr) * 32 + rc];
#pragma unroll
        for (int ni = 0; ni < 4; ++ni)
            bfv[ni] = *(const bf16x8*)&Bs[bsel][(wc + ni * 16 + fr) * 32 + rc];
        __builtin_amdgcn_s_setprio(1);
#pragma unroll
        for (int mi = 0; mi < 4; ++mi)
#pragma unroll
            for (int ni = 0; ni < 4; ++ni)
                acc[mi][ni] = __builtin_amdgcn_mfma_f32_16x16x32_bf16(af[mi], bfv[ni], acc[mi][ni], 0, 0, 0);
        __builtin_amdgcn_s_setprio(0);
    };

    const int nt = K >> 5;
    stage(0, 0);
    stage(1, 32);
    int cur = 0;
#pragma unroll 1
    for (int t = 0; t < nt; ++t) {
        if (t < nt - 1) asm volatile("s_waitcnt vmcnt(4)" ::: "memory");
        else            asm volatile("s_waitcnt vmcnt(0)" ::: "memory");
        __builtin_amdgcn_s_barrier();
        compute(cur);
        if (t + 2 < nt) {
            int nxt = cur + 2; if (nxt >= 3) nxt -= 3;
            stage(nxt, (t + 2) << 5);
        }
        cur = (cur + 1 == 3) ? 0 : cur + 1;
    }

#pragma unroll
    for (int mi = 0; mi < 4; ++mi) {
#pragma unroll
        for (int ni = 0; ni < 4; ++ni) {
            int row = rowb * 128 + wr + mi * 16 + g * 4;
            int col = colb * 128 + wc + ni * 16 + fr;
            float bz = bias[col];
#pragma unroll
            for (int r = 0; r < 4; ++r)
                Cout[(size_t)(row + r) * N + col] = acc[mi][ni][r] + bz;
        }
    }
}

// ---------------- flash attention: 256-thr blocks, independent barrier domains ----------------
// Each block: 4 waves x 32 q-rows = 128 q, loops ALL 32 KV tiles (no KV-split, no merge).
// Grid 512 -> 2 blocks/CU; each SIMD hosts waves from 2 independently-barriered blocks,
// so one block's exp/pack VALU overlaps the other's MFMA (m114 co-scheduling).
__global__ __launch_bounds__(256, 4)
void k_attn(const unsigned short* __restrict__ Qb,
            const unsigned short* __restrict__ Kb,
            const unsigned short* __restrict__ VT,
            unsigned short* __restrict__ Ob) {
    __shared__ unsigned short smem[2][2][4096];   // [K/V][bsel] = 32 KB
    const int tid = threadIdx.x, lane = tid & 63, w = tid >> 6;   // w 0..3
    const int l31 = lane & 31, hi = lane >> 5;
    const int bid = blockIdx.x;
    const int loc = bid >> 3;                     // 0..63
    const int bh = (bid & 7) * 4 + (loc >> 4);    // XCD-grouped: 4 heads/XCD
    const int qb = loc & 15;
    const int b = bh >> 3, h = bh & 7;
    const int qr0 = qb * 128 + w * 32;
    const unsigned short* Q = Qb + (size_t)bh * 2048 * 64;
    const unsigned short* K = Kb + (size_t)bh * 2048 * 64;
    const unsigned short* V = VT + (size_t)bh * 64 * 2048;

    const int srow8 = lane >> 3;
    const int swc = ((lane & 7) ^ srow8) << 3;
    const int sA = w, sB = w + 4;

    // Q as B-fragments: bq[ds] = Q[q=l31][d = ds*16 + hi*8 + 0..7]
    bf16x8 bq[4];
#pragma unroll
    for (int ds = 0; ds < 4; ++ds)
        bq[ds] = *(const bf16x8*)&Q[(size_t)(qr0 + l31) * 64 + ds * 16 + hi * 8];

    f32x16 oT0, oT1;
#pragma unroll
    for (int i = 0; i < 16; ++i) { oT0[i] = 0.f; oT1[i] = 0.f; }
    float lpart = 0.f;

    auto stage = [&](int bsel, int t) {
        const int kv0 = t * 64;
        const unsigned short* k0 = K + (size_t)(kv0 + sA * 8 + srow8) * 64 + swc;
        const unsigned short* k1 = K + (size_t)(kv0 + sB * 8 + srow8) * 64 + swc;
        const unsigned short* v0 = V + (size_t)(sA * 8 + srow8) * 2048 + kv0 + swc;
        const unsigned short* v1 = V + (size_t)(sB * 8 + srow8) * 2048 + kv0 + swc;
        char* dk = (char*)&smem[0][bsel][0];
        char* dv = (char*)&smem[1][bsel][0];
        __builtin_amdgcn_global_load_lds((const __attribute__((address_space(1))) void*)k0,
                                         (__attribute__((address_space(3))) void*)(dk + sA * 1024), 16, 0, 0);
        __builtin_amdgcn_global_load_lds((const __attribute__((address_space(1))) void*)k1,
                                         (__attribute__((address_space(3))) void*)(dk + sB * 1024), 16, 0, 0);
        __builtin_amdgcn_global_load_lds((const __attribute__((address_space(1))) void*)v0,
                                         (__attribute__((address_space(3))) void*)(dv + sA * 1024), 16, 0, 0);
        __builtin_amdgcn_global_load_lds((const __attribute__((address_space(1))) void*)v1,
                                         (__attribute__((address_space(3))) void*)(dv + sB * 1024), 16, 0, 0);
    };

    auto pack8 = [&](const float* p) -> bf16x8 {
        union { unsigned int u[4]; bf16x8 v; } c;
        c.u[0] = cvt_pk_bf16(p[0], p[1]);
        c.u[1] = cvt_pk_bf16(p[2], p[3]);
        c.u[2] = cvt_pk_bf16(p[4], p[5]);
        c.u[3] = cvt_pk_bf16(p[6], p[7]);
        return c.v;
    };

    auto compute = [&](int bsel) {
        const unsigned short* KsC = &smem[0][bsel][0];
        const unsigned short* VtC = &smem[1][bsel][0];
        f32x16 s0, s1;
#pragma unroll
        for (int i = 0; i < 16; ++i) { s0[i] = 0.f; s1[i] = 0.f; }
        __builtin_amdgcn_s_setprio(1);
#pragma unroll
        for (int ds = 0; ds < 4; ++ds) {
            const int c = ((((ds << 1) | hi) ^ (l31 & 7)) << 3);
            bf16x8 ka0 = *(const bf16x8*)&KsC[l31 * 64 + c];
            bf16x8 ka1 = *(const bf16x8*)&KsC[(32 + l31) * 64 + c];
            s0 = __builtin_amdgcn_mfma_f32_32x32x16_bf16(ka0, bq[ds], s0, 0, 0, 0);
            s1 = __builtin_amdgcn_mfma_f32_32x32x16_bf16(ka1, bq[ds], s1, 0, 0, 0);
        }
        __builtin_amdgcn_s_setprio(0);
        float p0[16], p1[16];
        float lsum = 0.f;
#pragma unroll
        for (int r = 0; r < 16; ++r) {
            p0[r] = fexp2(s0[r]);
            p1[r] = fexp2(s1[r]);
            lsum += p0[r] + p1[r];
        }
        lpart += lsum;
        bf16x8 pb0 = pack8(p0);
        bf16x8 pb1 = pack8(p0 + 8);
        bf16x8 pb2 = pack8(p1);
        bf16x8 pb3 = pack8(p1 + 8);
        __builtin_amdgcn_s_setprio(1);
#pragma unroll
        for (int kb = 0; kb < 4; ++kb) {
            const int c = ((((kb << 1) | hi) ^ (l31 & 7)) << 3);
            bf16x8 av0 = *(const bf16x8*)&VtC[l31 * 64 + c];
            bf16x8 av1 = *(const bf16x8*)&VtC[(32 + l31) * 64 + c];
            bf16x8 pbk = (kb == 0) ? pb0 : (kb == 1) ? pb1 : (kb == 2) ? pb2 : pb3;
            oT0 = __builtin_amdgcn_mfma_f32_32x32x16_bf16(av0, pbk, oT0, 0, 0, 0);
            oT1 = __builtin_amdgcn_mfma_f32_32x32x16_bf16(av1, pbk, oT1, 0, 0, 0);
        }
        __builtin_amdgcn_s_setprio(0);
    };

    stage(0, 0);
    asm volatile("s_waitcnt vmcnt(0)" ::: "memory");   // Q + first stage landed
    __builtin_amdgcn_s_barrier();
    int cur = 0;
#pragma unroll 1
    for (int t = 0; t < 32; ++t) {
        if (t < 31) stage(cur ^ 1, t + 1);
        compute(cur);
        if (t < 31) {
            asm volatile("s_waitcnt vmcnt(0)" ::: "memory"); // own stage landed (hidden by compute)
            __builtin_amdgcn_s_barrier();                    // publish buf[cur^1]; buf[cur] consumed
        }
        cur ^= 1;
    }

    // direct epilogue: q = l31 lane-local; no cross-block merge needed
    float lf = lpart + __shfl_xor(lpart, 32, 64);
    float il = 1.f / lf;
    size_t rowbase = (size_t)(b * 2048 + qr0 + l31) * 512 + h * 64;
#pragma unroll
    for (int grp = 0; grp < 4; ++grp) {
        u16x4 o0, o1;
#pragma unroll
        for (int i = 0; i < 4; ++i) {
            o0[i] = f2bf(oT0[grp * 4 + i] * il);
            o1[i] = f2bf(oT1[grp * 4 + i] * il);
        }
        int dv0 = grp * 8 + 4 * hi;
        *(u16x4*)&Ob[rowbase + dv0] = o0;
        *(u16x4*)&Ob[rowbase + 32 + dv0] = o1;
    }
}

extern "C" void kernel_launch(void* const* d_in, const int* in_sizes, int n_in,
                              void* d_out, int out_size, void* d_ws, size_t ws_size,
                              hipStream_t stream) {
    const float* x     = (const float*)d_in[0];
    const float* pos   = (const float*)d_in[1];
    const float* qkv_w = (const float*)d_in[2];
    const float* qkv_b = (const float*)d_in[3];
    const float* out_w = (const float*)d_in[4];
    const float* out_b = (const float*)d_in[5];
    float* out = (float*)d_out;

    unsigned short* Xb   = (unsigned short*)d_ws;
    unsigned short* W1b  = Xb   + (size_t)8192 * 512;
    unsigned short* W2b  = W1b  + (size_t)1536 * 512;
    unsigned short* Qb   = W2b  + (size_t)512 * 512;
    unsigned short* Kb   = Qb   + (size_t)4194304;
    unsigned short* VTb  = Kb   + (size_t)4194304;
    unsigned short* Ob   = VTb  + (size_t)4194304;

    k_cvt3<<<5120, 256, 0, stream>>>(x, qkv_w, out_w, Xb);
    k_gemm_qkv<<<768, 256, 0, stream>>>(Xb, W1b, qkv_b, pos, Qb, Kb, VTb);
    k_attn<<<512, 256, 0, stream>>>(Qb, Kb, VTb, Ob);
    k_gemm_out<<<256, 256, 0, stream>>>(Ob, W2b, out_b, out, 8192, 512, 512);
}

// Round 19
// 82.977 us; speedup vs baseline: 1.0464x; 1.0464x over previous
//
#include <hip/hip_runtime.h>
#include <stdint.h>

typedef __attribute__((ext_vector_type(4))) float f32x4;
typedef __attribute__((ext_vector_type(16))) float f32x16;
typedef __attribute__((ext_vector_type(8))) short bf16x8;
typedef __attribute__((ext_vector_type(4))) unsigned short u16x4;

__device__ __forceinline__ unsigned short f2bf(float f) {
    unsigned int u = __builtin_bit_cast(unsigned int, f);
    u += 0x7fffu + ((u >> 16) & 1u);
    return (unsigned short)(u >> 16);
}
__device__ __forceinline__ float bf2f(unsigned short s) {
    unsigned int u = ((unsigned int)s) << 16;
    return __builtin_bit_cast(float, u);
}
__device__ __forceinline__ float fexp2(float x) {
#if __has_builtin(__builtin_amdgcn_exp2f)
    return __builtin_amdgcn_exp2f(x);
#else
    return exp2f(x);
#endif
}
__device__ __forceinline__ unsigned int cvt_pk_bf16(float lo, float hi) {
    unsigned int r;
    asm("v_cvt_pk_bf16_f32 %0, %1, %2" : "=v"(r) : "v"(lo), "v"(hi));
    return r;
}

// ---------------- fused f32 -> bf16 convert of x, qkv_w, out_w ----------------
__global__ void k_cvt3(const float* __restrict__ x,
                       const float* __restrict__ w1,
                       const float* __restrict__ w2,
                       unsigned short* __restrict__ out) {
    const int C1 = 1048576;            // x chunks (8192*512/4)
    const int C2 = 196608;             // w1 chunks (1536*512/4)
    int i = blockIdx.x * blockDim.x + threadIdx.x;
    f32x4 v;
    if (i < C1)            v = ((const f32x4*)x)[i];
    else if (i < C1 + C2)  v = ((const f32x4*)w1)[i - C1];
    else                   v = ((const f32x4*)w2)[i - C1 - C2];
    u16x4 o;
    o.x = f2bf(v.x); o.y = f2bf(v.y); o.z = f2bf(v.z); o.w = f2bf(v.w);
    ((u16x4*)out)[i] = o;
}

// ---------------- GEMM1 + fused rotary/split/transpose epilogue ----------------
__global__ __launch_bounds__(256, 3)
void k_gemm_qkv(const unsigned short* __restrict__ A,
                const unsigned short* __restrict__ Bm,
                const float* __restrict__ bias,
                const float* __restrict__ pos,
                unsigned short* __restrict__ Qb,
                unsigned short* __restrict__ Kb,
                unsigned short* __restrict__ VT) {
    const float PI = 3.14159265358979323846f;
    const float QS = 0.04419417382415922f * 1.44269504088896341f;  // scale * log2(e)
    const int K = 512;
    __shared__ unsigned short As[3][128 * 32];
    __shared__ unsigned short Bs[3][128 * 32];
    const int tid = threadIdx.x;
    const int lane = tid & 63;
    const int w = tid >> 6;
    const int wr = (w >> 1) * 64, wc = (w & 1) * 64;
    const int g = lane >> 4, fr = lane & 15;

    const int bid = blockIdx.x;
    const int xcd = bid & 7, loc = bid >> 3;
    const int rowb = xcd * 8 + (loc & 7);
    const int colb = loc >> 3;                 // 0..11

    f32x4 acc[4][4];
#pragma unroll
    for (int i = 0; i < 4; ++i)
#pragma unroll
        for (int j = 0; j < 4; ++j) acc[i][j] = f32x4{0.f, 0.f, 0.f, 0.f};

    const int srow16 = lane >> 2;
    const int schunk = ((lane & 3) ^ (srow16 & 3)) * 8;
    const int sA = w, sB = w + 4;
    const unsigned short* Aseg0 = A + (size_t)(rowb * 128 + sA * 16 + srow16) * K + schunk;
    const unsigned short* Aseg1 = A + (size_t)(rowb * 128 + sB * 16 + srow16) * K + schunk;
    const unsigned short* Bseg0 = Bm + (size_t)(colb * 128 + sA * 16 + srow16) * K + schunk;
    const unsigned short* Bseg1 = Bm + (size_t)(colb * 128 + sB * 16 + srow16) * K + schunk;

    auto stage = [&](int bsel, int k0) {
        char* la = (char*)&As[bsel][0];
        char* lb = (char*)&Bs[bsel][0];
        __builtin_amdgcn_global_load_lds((const __attribute__((address_space(1))) void*)(Aseg0 + k0),
                                         (__attribute__((address_space(3))) void*)(la + sA * 1024), 16, 0, 0);
        __builtin_amdgcn_global_load_lds((const __attribute__((address_space(1))) void*)(Aseg1 + k0),
                                         (__attribute__((address_space(3))) void*)(la + sB * 1024), 16, 0, 0);
        __builtin_amdgcn_global_load_lds((const __attribute__((address_space(1))) void*)(Bseg0 + k0),
                                         (__attribute__((address_space(3))) void*)(lb + sA * 1024), 16, 0, 0);
        __builtin_amdgcn_global_load_lds((const __attribute__((address_space(1))) void*)(Bseg1 + k0),
                                         (__attribute__((address_space(3))) void*)(lb + sB * 1024), 16, 0, 0);
    };
    auto compute = [&](int bsel) {
        bf16x8 af[4], bfv[4];
        const int rc = (g ^ (fr & 3)) * 8;
#pragma unroll
        for (int mi = 0; mi < 4; ++mi)
            af[mi] = *(const bf16x8*)&As[bsel][(wr + mi * 16 + fr) * 32 + rc];
#pragma unroll
        for (int ni = 0; ni < 4; ++ni)
            bfv[ni] = *(const bf16x8*)&Bs[bsel][(wc + ni * 16 + fr) * 32 + rc];
        __builtin_amdgcn_s_setprio(1);
#pragma unroll
        for (int mi = 0; mi < 4; ++mi)
#pragma unroll
            for (int ni = 0; ni < 4; ++ni)
                acc[mi][ni] = __builtin_amdgcn_mfma_f32_16x16x32_bf16(af[mi], bfv[ni], acc[mi][ni], 0, 0, 0);
        __builtin_amdgcn_s_setprio(0);
    };

    const int nt = K >> 5;
    stage(0, 0);
    stage(1, 32);
    int cur = 0;
#pragma unroll 1
    for (int t = 0; t < nt; ++t) {
        if (t < nt - 1) asm volatile("s_waitcnt vmcnt(4)" ::: "memory");
        else            asm volatile("s_waitcnt vmcnt(0)" ::: "memory");
        __builtin_amdgcn_s_barrier();
        compute(cur);
        if (t + 2 < nt) {
            int nxt = cur + 2; if (nxt >= 3) nxt -= 3;
            stage(nxt, (t + 2) << 5);
        }
        cur = (cur + 1 == 3) ? 0 : cur + 1;
    }

    const int jrot = (fr < 3) ? fr : ((fr < 6) ? fr - 3 : 0);
    const int shbase = lane & 48;
#pragma unroll
    for (int mi = 0; mi < 4; ++mi) {
#pragma unroll
        for (int ni = 0; ni < 4; ++ni) {
            int row = rowb * 128 + wr + mi * 16 + g * 4;
            int col = colb * 128 + wc + ni * 16 + fr;
            float bz = bias[col];
            float v[4];
#pragma unroll
            for (int r = 0; r < 4; ++r) v[r] = acc[mi][ni][r] + bz;
            int b = row >> 11, n = row & 2047;
            if (colb < 8) {
                const int isQ = (colb < 4);
                int qcol = isQ ? col : col - 512;
                int h = qcol >> 6, dh = qcol & 63;
                if (ni == 0) {   // dh 0..15 sub-block: rotate dh<6
#pragma unroll
                    for (int r = 0; r < 4; ++r) {
                        float x1 = __shfl(v[r], shbase + 2 * jrot, 64);
                        float x2 = __shfl(v[r], shbase + 2 * jrot + 1, 64);
                        if (fr < 6) {
                            float th = pos[(row + r) * 3 + jrot] * PI;
                            float sn = __sinf(th), cs = __cosf(th);
                            v[r] = (fr < 3) ? (x1 * cs - x2 * sn) : (x1 * sn + x2 * cs);
                        }
                    }
                }
                float qs = isQ ? QS : 1.f;
                unsigned short* dst = isQ ? Qb : Kb;
                size_t rb = (size_t)(b * 8 + h) * 2048 + n;
#pragma unroll
                for (int r = 0; r < 4; ++r)
                    dst[(rb + r) * 64 + dh] = f2bf(v[r] * qs);
            } else {
                int vcol = col - 1024;
                int h = vcol >> 6, dh = vcol & 63;
                int q2 = (n >> 2) & 3;
                int np = n + (q2 == 1 ? 4 : (q2 == 2 ? -4 : 0));
                u16x4 o;
#pragma unroll
                for (int r = 0; r < 4; ++r) o[r] = f2bf(v[r]);
                *(u16x4*)&VT[((size_t)(b * 8 + h) * 64 + dh) * 2048 + np] = o;
            }
        }
    }
}

// ---------------- NT GEMM (out-proj): BK=32, 3-buffer, XCD-grouped ----------------
__global__ __launch_bounds__(256, 3)
void k_gemm_out(const unsigned short* __restrict__ A,
                const unsigned short* __restrict__ Bm,
                const float* __restrict__ bias,
                float* __restrict__ Cout, int M, int N, int K) {
    __shared__ unsigned short As[3][128 * 32];
    __shared__ unsigned short Bs[3][128 * 32];
    const int tid = threadIdx.x;
    const int lane = tid & 63;
    const int w = tid >> 6;
    const int wr = (w >> 1) * 64, wc = (w & 1) * 64;
    const int g = lane >> 4, fr = lane & 15;

    const int bid = blockIdx.x;
    const int xcd = bid & 7, loc = bid >> 3;
    const int rowb = xcd * 8 + (loc & 7);
    const int colb = loc >> 3;

    f32x4 acc[4][4];
#pragma unroll
    for (int i = 0; i < 4; ++i)
#pragma unroll
        for (int j = 0; j < 4; ++j) acc[i][j] = f32x4{0.f, 0.f, 0.f, 0.f};

    const int srow16 = lane >> 2;
    const int schunk = ((lane & 3) ^ (srow16 & 3)) * 8;
    const int sA = w, sB = w + 4;
    const unsigned short* Aseg0 = A + (size_t)(rowb * 128 + sA * 16 + srow16) * K + schunk;
    const unsigned short* Aseg1 = A + (size_t)(rowb * 128 + sB * 16 + srow16) * K + schunk;
    const unsigned short* Bseg0 = Bm + (size_t)(colb * 128 + sA * 16 + srow16) * K + schunk;
    const unsigned short* Bseg1 = Bm + (size_t)(colb * 128 + sB * 16 + srow16) * K + schunk;

    auto stage = [&](int bsel, int k0) {
        char* la = (char*)&As[bsel][0];
        char* lb = (char*)&Bs[bsel][0];
        __builtin_amdgcn_global_load_lds((const __attribute__((address_space(1))) void*)(Aseg0 + k0),
                                         (__attribute__((address_space(3))) void*)(la + sA * 1024), 16, 0, 0);
        __builtin_amdgcn_global_load_lds((const __attribute__((address_space(1))) void*)(Aseg1 + k0),
                                         (__attribute__((address_space(3))) void*)(la + sB * 1024), 16, 0, 0);
        __builtin_amdgcn_global_load_lds((const __attribute__((address_space(1))) void*)(Bseg0 + k0),
                                         (__attribute__((address_space(3))) void*)(lb + sA * 1024), 16, 0, 0);
        __builtin_amdgcn_global_load_lds((const __attribute__((address_space(1))) void*)(Bseg1 + k0),
                                         (__attribute__((address_space(3))) void*)(lb + sB * 1024), 16, 0, 0);
    };
    auto compute = [&](int bsel) {
        bf16x8 af[4], bfv[4];
        const int rc = (g ^ (fr & 3)) * 8;
#pragma unroll
        for (int mi = 0; mi < 4; ++mi)
            af[mi] = *(const bf16x8*)&As[bsel][(wr + mi * 16 + fr) * 32 + rc];
#pragma unroll
        for (int ni = 0; ni < 4; ++ni)
            bfv[ni] = *(const bf16x8*)&Bs[bsel][(wc + ni * 16 + fr) * 32 + rc];
        __builtin_amdgcn_s_setprio(1);
#pragma unroll
        for (int mi = 0; mi < 4; ++mi)
#pragma unroll
            for (int ni = 0; ni < 4; ++ni)
                acc[mi][ni] = __builtin_amdgcn_mfma_f32_16x16x32_bf16(af[mi], bfv[ni], acc[mi][ni], 0, 0, 0);
        __builtin_amdgcn_s_setprio(0);
    };

    const int nt = K >> 5;
    stage(0, 0);
    stage(1, 32);
    int cur = 0;
#pragma unroll 1
    for (int t = 0; t < nt; ++t) {
        if (t < nt - 1) asm volatile("s_waitcnt vmcnt(4)" ::: "memory");
        else            asm volatile("s_waitcnt vmcnt(0)" ::: "memory");
        __builtin_amdgcn_s_barrier();
        compute(cur);
        if (t + 2 < nt) {
            int nxt = cur + 2; if (nxt >= 3) nxt -= 3;
            stage(nxt, (t + 2) << 5);
        }
        cur = (cur + 1 == 3) ? 0 : cur + 1;
    }

#pragma unroll
    for (int mi = 0; mi < 4; ++mi) {
#pragma unroll
        for (int ni = 0; ni < 4; ++ni) {
            int row = rowb * 128 + wr + mi * 16 + g * 4;
            int col = colb * 128 + wc + ni * 16 + fr;
            float bz = bias[col];
#pragma unroll
            for (int r = 0; r < 4; ++r)
                Cout[(size_t)(row + r) * N + col] = acc[mi][ni][r] + bz;
        }
    }
}

// ---------------- flash attention: 64 q-rows/wave (2 subtiles), KV-split x2 ----------------
__global__ __launch_bounds__(512, 2)
void k_attn(const unsigned short* __restrict__ Qb,
            const unsigned short* __restrict__ Kb,
            const unsigned short* __restrict__ VT,
            unsigned short* __restrict__ Ob) {
    __shared__ unsigned short smem[2][2][2][4096];   // [half][K/V][bsel][64*64] = 64 KB
    const int tid = threadIdx.x, lane = tid & 63, w = tid >> 6;
    const int wl = w & 3, half = w >> 2;
    const int l31 = lane & 31, hi = lane >> 5;
    const int bid = blockIdx.x;
    const int loc = bid >> 3;
    const int bh = (bid & 7) * 4 + (loc >> 3);          // XCD-grouped: 4 heads/XCD
    const int qb = loc & 7;
    const int b = bh >> 3, h = bh & 7;
    const int qr0 = qb * 256 + wl * 64;
    const unsigned short* Q = Qb + (size_t)bh * 2048 * 64;
    const unsigned short* K = Kb + (size_t)bh * 2048 * 64;
    const unsigned short* V = VT + (size_t)bh * 64 * 2048;
    const int thalf = half * 16;

    const int srow8 = lane >> 3;
    const int swc = ((lane & 7) ^ srow8) << 3;
    const int sA = wl, sB = wl + 4;

    bf16x8 bq0[4], bq1[4];
#pragma unroll
    for (int ds = 0; ds < 4; ++ds) {
        bq0[ds] = *(const bf16x8*)&Q[(size_t)(qr0 + l31) * 64 + ds * 16 + hi * 8];
        bq1[ds] = *(const bf16x8*)&Q[(size_t)(qr0 + 32 + l31) * 64 + ds * 16 + hi * 8];
    }

    f32x16 oT00, oT01, oT10, oT11;
#pragma unroll
    for (int i = 0; i < 16; ++i) { oT00[i] = 0.f; oT01[i] = 0.f; oT10[i] = 0.f; oT11[i] = 0.f; }
    float lp0 = 0.f, lp1 = 0.f;

    auto stage = [&](int bsel, int t) {
        const int kv0 = t * 64;
        const unsigned short* k0 = K + (size_t)(kv0 + sA * 8 + srow8) * 64 + swc;
        const unsigned short* k1 = K + (size_t)(kv0 + sB * 8 + srow8) * 64 + swc;
        const unsigned short* v0 = V + (size_t)(sA * 8 + srow8) * 2048 + kv0 + swc;
        const unsigned short* v1 = V + (size_t)(sB * 8 + srow8) * 2048 + kv0 + swc;
        char* dk = (char*)&smem[half][0][bsel][0];
        char* dv = (char*)&smem[half][1][bsel][0];
        __builtin_amdgcn_global_load_lds((const __attribute__((address_space(1))) void*)k0,
                                         (__attribute__((address_space(3))) void*)(dk + sA * 1024), 16, 0, 0);
        __builtin_amdgcn_global_load_lds((const __attribute__((address_space(1))) void*)k1,
                                         (__attribute__((address_space(3))) void*)(dk + sB * 1024), 16, 0, 0);
        __builtin_amdgcn_global_load_lds((const __attribute__((address_space(1))) void*)v0,
                                         (__attribute__((address_space(3))) void*)(dv + sA * 1024), 16, 0, 0);
        __builtin_amdgcn_global_load_lds((const __attribute__((address_space(1))) void*)v1,
                                         (__attribute__((address_space(3))) void*)(dv + sB * 1024), 16, 0, 0);
    };

    auto pack8 = [&](const float* p) -> bf16x8 {
        union { unsigned int u[4]; bf16x8 v; } c;
        c.u[0] = cvt_pk_bf16(p[0], p[1]);
        c.u[1] = cvt_pk_bf16(p[2], p[3]);
        c.u[2] = cvt_pk_bf16(p[4], p[5]);
        c.u[3] = cvt_pk_bf16(p[6], p[7]);
        return c.v;
    };

    auto compute = [&](int bsel) {
        const unsigned short* KsC = &smem[half][0][bsel][0];
        const unsigned short* VtC = &smem[half][1][bsel][0];
        bf16x8 pb0[4], pb1[4];
        {
            f32x16 s0, s1;
#pragma unroll
            for (int i = 0; i < 16; ++i) { s0[i] = 0.f; s1[i] = 0.f; }
            __builtin_amdgcn_s_setprio(1);
#pragma unroll
            for (int ds = 0; ds < 4; ++ds) {
                const int c = ((((ds << 1) | hi) ^ (l31 & 7)) << 3);
                bf16x8 ka0 = *(const bf16x8*)&KsC[l31 * 64 + c];
                bf16x8 ka1 = *(const bf16x8*)&KsC[(32 + l31) * 64 + c];
                s0 = __builtin_amdgcn_mfma_f32_32x32x16_bf16(ka0, bq0[ds], s0, 0, 0, 0);
                s1 = __builtin_amdgcn_mfma_f32_32x32x16_bf16(ka1, bq0[ds], s1, 0, 0, 0);
            }
            __builtin_amdgcn_s_setprio(0);
            float p0[16], p1[16], lsum = 0.f;
#pragma unroll
            for (int r = 0; r < 16; ++r) {
                p0[r] = fexp2(s0[r]);
                p1[r] = fexp2(s1[r]);
                lsum += p0[r] + p1[r];
            }
            lp0 += lsum;
            pb0[0] = pack8(p0); pb0[1] = pack8(p0 + 8);
            pb0[2] = pack8(p1); pb0[3] = pack8(p1 + 8);
        }
        {
            f32x16 s0, s1;
#pragma unroll
            for (int i = 0; i < 16; ++i) { s0[i] = 0.f; s1[i] = 0.f; }
            __builtin_amdgcn_s_setprio(1);
#pragma unroll
            for (int ds = 0; ds < 4; ++ds) {
                const int c = ((((ds << 1) | hi) ^ (l31 & 7)) << 3);
                bf16x8 ka0 = *(const bf16x8*)&KsC[l31 * 64 + c];
                bf16x8 ka1 = *(const bf16x8*)&KsC[(32 + l31) * 64 + c];
                s0 = __builtin_amdgcn_mfma_f32_32x32x16_bf16(ka0, bq1[ds], s0, 0, 0, 0);
                s1 = __builtin_amdgcn_mfma_f32_32x32x16_bf16(ka1, bq1[ds], s1, 0, 0, 0);
            }
            __builtin_amdgcn_s_setprio(0);
            __builtin_amdgcn_s_setprio(1);
#pragma unroll
            for (int kb = 0; kb < 4; ++kb) {
                const int c = ((((kb << 1) | hi) ^ (l31 & 7)) << 3);
                bf16x8 av0 = *(const bf16x8*)&VtC[l31 * 64 + c];
                bf16x8 av1 = *(const bf16x8*)&VtC[(32 + l31) * 64 + c];
                oT00 = __builtin_amdgcn_mfma_f32_32x32x16_bf16(av0, pb0[kb], oT00, 0, 0, 0);
                oT01 = __builtin_amdgcn_mfma_f32_32x32x16_bf16(av1, pb0[kb], oT01, 0, 0, 0);
            }
            __builtin_amdgcn_s_setprio(0);
            float p0[16], p1[16], lsum = 0.f;
#pragma unroll
            for (int r = 0; r < 16; ++r) {
                p0[r] = fexp2(s0[r]);
                p1[r] = fexp2(s1[r]);
                lsum += p0[r] + p1[r];
            }
            lp1 += lsum;
            pb1[0] = pack8(p0); pb1[1] = pack8(p0 + 8);
            pb1[2] = pack8(p1); pb1[3] = pack8(p1 + 8);
        }
        __builtin_amdgcn_s_setprio(1);
#pragma unroll
        for (int kb = 0; kb < 4; ++kb) {
            const int c = ((((kb << 1) | hi) ^ (l31 & 7)) << 3);
            bf16x8 av0 = *(const bf16x8*)&VtC[l31 * 64 + c];
            bf16x8 av1 = *(const bf16x8*)&VtC[(32 + l31) * 64 + c];
            oT10 = __builtin_amdgcn_mfma_f32_32x32x16_bf16(av0, pb1[kb], oT10, 0, 0, 0);
            oT11 = __builtin_amdgcn_mfma_f32_32x32x16_bf16(av1, pb1[kb], oT11, 0, 0, 0);
        }
        __builtin_amdgcn_s_setprio(0);
    };

    stage(0, thalf);
    asm volatile("s_waitcnt vmcnt(0)" ::: "memory");   // Q + first stage landed
    __builtin_amdgcn_s_barrier();
    int cur = 0;
#pragma unroll 1
    for (int t = 0; t < 16; ++t) {
        if (t < 15) stage(cur ^ 1, thalf + t + 1);
        compute(cur);
        if (t < 15) {
            asm volatile("s_waitcnt vmcnt(0)" ::: "memory"); // own stage landed (hidden by compute)
            __builtin_amdgcn_s_barrier();                    // publish buf[cur^1]; buf[cur] consumed
        }
        cur ^= 1;
    }

    // merge the two KV halves through LDS, one subtile at a time (33KB area)
    float* mrg = (float*)&smem[0][0][0][0];
    float* slot = mrg + (size_t)(wl * 64 + lane) * 33;
#pragma unroll 1
    for (int st = 0; st < 2; ++st) {
        f32x16& a0 = st ? oT10 : oT00;
        f32x16& a1 = st ? oT11 : oT01;
        float lp = st ? lp1 : lp0;
        __syncthreads();
        if (half) {
#pragma unroll
            for (int i = 0; i < 16; ++i) { slot[i] = a0[i]; slot[16 + i] = a1[i]; }
            slot[32] = lp;
        }
        __syncthreads();
        if (!half) {
            float lf = lp + slot[32];
            lf += __shfl_xor(lf, 32, 64);
            float il = 1.f / lf;
            size_t rowbase = (size_t)(b * 2048 + qr0 + st * 32 + l31) * 512 + h * 64;
#pragma unroll
            for (int grp = 0; grp < 4; ++grp) {
                u16x4 o0, o1;
#pragma unroll
                for (int i = 0; i < 4; ++i) {
                    o0[i] = f2bf((a0[grp * 4 + i] + slot[grp * 4 + i]) * il);
                    o1[i] = f2bf((a1[grp * 4 + i] + slot[16 + grp * 4 + i]) * il);
                }
                int dv0 = grp * 8 + 4 * hi;
                *(u16x4*)&Ob[rowbase + dv0] = o0;
                *(u16x4*)&Ob[rowbase + 32 + dv0] = o1;
            }
        }
    }
}

extern "C" void kernel_launch(void* const* d_in, const int* in_sizes, int n_in,
                              void* d_out, int out_size, void* d_ws, size_t ws_size,
                              hipStream_t stream) {
    const float* x     = (const float*)d_in[0];
    const float* pos   = (const float*)d_in[1];
    const float* qkv_w = (const float*)d_in[2];
    const float* qkv_b = (const float*)d_in[3];
    const float* out_w = (const float*)d_in[4];
    const float* out_b = (const float*)d_in[5];
    float* out = (float*)d_out;

    unsigned short* Xb   = (unsigned short*)d_ws;
    unsigned short* W1b  = Xb   + (size_t)8192 * 512;
    unsigned short* W2b  = W1b  + (size_t)1536 * 512;
    unsigned short* Qb   = W2b  + (size_t)512 * 512;
    unsigned short* Kb   = Qb   + (size_t)4194304;
    unsigned short* VTb  = Kb   + (size_t)4194304;
    unsigned short* Ob   = VTb  + (size_t)4194304;

    k_cvt3<<<5120, 256, 0, stream>>>(x, qkv_w, out_w, Xb);
    k_gemm_qkv<<<768, 256, 0, stream>>>(Xb, W1b, qkv_b, pos, Qb, Kb, VTb);
    k_attn<<<256, 512, 0, stream>>>(Qb, Kb, VTb, Ob);
    k_gemm_out<<<256, 256, 0, stream>>>(Ob, W2b, out_b, out, 8192, 512, 512);
}